// Round 6
// baseline (202.907 us; speedup 1.0000x reference)
//
#include <hip/hip_runtime.h>
#include <hip/hip_bf16.h>

// CIN round 6: software-pipelined softmax<->MFMA (double-buffered s_XT,
// ONE barrier per chunk), register-direct xk/xv, all-wave softmax in both
// layers, single res buffer.
//
// GEMM per layer: out[b,j,k] = sum_c' X[b,k,c'] * Bp[c',j],  c' = fi*40+f0
// mfma_f32_32x32x16_bf16 frag maps: A[l&31][8*(l>>5)+i], B[8*(l>>5)+i][l&31],
// C/D: col=l&31, row=(reg&3)+8*(reg>>2)+4*(l>>5)   [C/D HW-verified m74/m101]

#define NF0  40
#define KD   32
#define NJ   200
#define NTHR 512

typedef short bf16x8 __attribute__((ext_vector_type(8)));
typedef float f32x16 __attribute__((ext_vector_type(16)));
typedef unsigned short u16;
typedef unsigned int   u32;
typedef unsigned long long u64;

static __device__ __forceinline__ u16 f2bf(float f) {
    __hip_bfloat16 h = __float2bfloat16(f);
    return *reinterpret_cast<u16*>(&h);
}
static __device__ __forceinline__ float bf2f(u16 u) {
    u32 x = ((u32)u) << 16;
    float f;
    __builtin_memcpy(&f, &x, 4);
    return f;
}

// ---- pack: cw [f0*FI+fi, 200] -> Bpack frag-major for 32x32x16, c'=fi*40+f0 ----
// Bpack[((nt*G + g)*64 + l)*8 + i] = B[c'=g*16+8*(l>>5)+i][j=nt*32+(l&31)]
template<int FI>
__global__ __launch_bounds__(256)
void pack_b(const float* __restrict__ cw, u16* __restrict__ bp, int G) {
    __shared__ u16 s[160][33];
    const int fi0 = blockIdx.x * 4;
    const int nt  = blockIdx.y;
    const int t   = threadIdx.x;
    #pragma unroll
    for (int it = 0; it < 5; ++it) {
        int idx = it * 256 + t;
        int rl = idx >> 3, q4 = idx & 7;
        int f0 = rl >> 2, fl = rl & 3;
        int fi = fi0 + fl;
        int j0 = nt * 32 + q4 * 4;
        float4 v = make_float4(0.f, 0.f, 0.f, 0.f);
        if (fi < FI && j0 <= NJ - 4)
            v = *reinterpret_cast<const float4*>(cw + (size_t)(f0 * FI + fi) * NJ + j0);
        int cl = fl * 40 + f0;
        s[cl][q4 * 4 + 0] = f2bf(v.x);
        s[cl][q4 * 4 + 1] = f2bf(v.y);
        s[cl][q4 * 4 + 2] = f2bf(v.z);
        s[cl][q4 * 4 + 3] = f2bf(v.w);
    }
    __syncthreads();
    for (int ft = t; ft < 640; ft += 256) {
        int g = ft >> 6, l = ft & 63;
        u16 v[8];
        #pragma unroll
        for (int i = 0; i < 8; ++i) v[i] = s[g * 16 + 8 * (l >> 5) + i][l & 31];
        *reinterpret_cast<bf16x8*>(bp + ((size_t)(nt * G + blockIdx.x * 10 + g) * 64 + l) * 8)
            = *reinterpret_cast<const bf16x8*>(v);
    }
}

// ---- layer 0: grid 256 (1 batch/block), chunk = 8 fi, 5 chunks, pipelined ----
__global__ __launch_bounds__(NTHR, 2)
void cin_layer0(const float* __restrict__ x0,
                const float* __restrict__ wq, const float* __restrict__ wk,
                const float* __restrict__ wv,
                const u16* __restrict__ bp, u16* __restrict__ resp) {
    __shared__ float s_q[1280];
    __shared__ u64 s_XT[2][32 * 96];          // 2 x 32 rows x 768 B = 48 KB

    const int tid = threadIdx.x;
    const int b = blockIdx.x;
    const int wid = tid >> 6, lane = tid & 63;
    const int sfil = wid, sh = lane >> 5, sk = lane & 31;

    for (int i = tid; i < 1280; i += NTHR)
        s_q[i] = x0[(size_t)b * 1280 + i] * wq[i];

    // chunk-invariant xk/xv: straight from global into registers
    float xkr[20], xvr[20];
    #pragma unroll
    for (int i = 0; i < 20; ++i) {
        const int off = (sh * 20 + i) * 32 + sk;
        const float v = x0[(size_t)b * 1280 + off];
        xkr[i] = v * wk[off];
        xvr[i] = v * wv[off];
    }

    const int soff = sfil * 80 + sh * 40;
    const int sswz = (sk & 7) << 4;
    char* srb0 = (char*)s_XT[0] + sk * 768;
    char* srb1 = (char*)s_XT[1] + sk * 768;

    const int nt = wid;                        // waves 0..6 own n-tiles
    const int arow = lane & 31;
    const int aswz = (arow & 7) << 4;
    char* apb0 = (char*)s_XT[0] + arow * 768;
    char* apb1 = (char*)s_XT[1] + arow * 768;
    const int ah = (lane >> 5) * 16;

    f32x16 acc;
    #pragma unroll
    for (int r = 0; r < 16; ++r) acc[r] = 0.f;

    auto softmax_store = [&](char* rb, int ch) {
        const float q = s_q[(ch * 8 + sfil) * 32 + sk];
        float e[20], d = 0.f;
        #pragma unroll
        for (int i = 0; i < 20; ++i) { e[i] = __expf(xkr[i] * q); d += e[i]; }
        d += __shfl_xor(d, 32);
        const float rr = 1.0f / d;
        #pragma unroll
        for (int p = 0; p < 5; ++p) {
            u64 w = (u64)f2bf(e[4*p+0] * rr * xvr[4*p+0])
                  | ((u64)f2bf(e[4*p+1] * rr * xvr[4*p+1]) << 16)
                  | ((u64)f2bf(e[4*p+2] * rr * xvr[4*p+2]) << 32)
                  | ((u64)f2bf(e[4*p+3] * rr * xvr[4*p+3]) << 48);
            *reinterpret_cast<u64*>(rb + ((soff + p * 8) ^ sswz)) = w;
        }
    };

    __syncthreads();                           // s_q ready
    softmax_store(srb0, 0);
    __syncthreads();

    for (int ch = 0; ch < 5; ++ch) {
        if (ch + 1 < 5) softmax_store((ch & 1) ? srb0 : srb1, ch + 1);
        if (wid < 7) {
            char* apb = (ch & 1) ? apb1 : apb0;
            #pragma unroll
            for (int ks = 0; ks < 20; ++ks) {
                bf16x8 a = *reinterpret_cast<const bf16x8*>(apb + ((ks * 32 + ah) ^ aswz));
                const int g = ch * 20 + ks;
                bf16x8 bf = *reinterpret_cast<const bf16x8*>(
                    bp + ((size_t)(nt * 100 + g) * 64 + lane) * 8);
                acc = __builtin_amdgcn_mfma_f32_32x32x16_bf16(a, bf, acc, 0, 0, 0);
            }
        }
        __syncthreads();
    }

    if (wid < 7) {
        const int j = nt * 32 + (lane & 31);
        if (j < NJ) {
            u16* dst = resp + (size_t)b * 6400 + j * 32;
            #pragma unroll
            for (int rg = 0; rg < 4; ++rg) {   // rows k = 8*rg + 4*hh + 0..3
                u64 w = (u64)f2bf(acc[4*rg+0]) | ((u64)f2bf(acc[4*rg+1]) << 16)
                      | ((u64)f2bf(acc[4*rg+2]) << 32) | ((u64)f2bf(acc[4*rg+3]) << 48);
                *reinterpret_cast<u64*>(dst + 8 * rg + 4 * (lane >> 5)) = w;
            }
        }
    }
}

// ---- layer 1: grid 512 = 128 bg(2 b) x 4 fi-splits (52 fi, 13 chunks), pipelined ----
__global__ __launch_bounds__(NTHR, 4)
void cin_layer1(const float* __restrict__ x0, const u16* __restrict__ resp,
                const float* __restrict__ wq, const float* __restrict__ wk,
                const float* __restrict__ wv,
                const u16* __restrict__ bp, float* __restrict__ out) {
    __shared__ float s_q[3328];               // 2 batches x 52 fi x 32 k
    __shared__ u64 s_XT[2][64 * 48];          // 2 x 64 rows x 384 B = 48 KB

    const int tid = threadIdx.x;
    const int bg = blockIdx.x >> 2, split = blockIdx.x & 3;
    const int b0 = bg * 2;
    const int wid = tid >> 6, lane = tid & 63;

    // split-0 duty: out[b, 0:200] = sum_k resp
    if (split == 0) {
        for (int idx = tid; idx < 2 * NJ; idx += NTHR) {
            const int bb = idx / NJ, j = idx - bb * NJ;
            const u16* rp = resp + (size_t)(b0 + bb) * 6400 + j * 32;
            float s = 0.f;
            #pragma unroll
            for (int q8 = 0; q8 < 4; ++q8) {
                bf16x8 v = *reinterpret_cast<const bf16x8*>(rp + q8 * 8);
                #pragma unroll
                for (int i = 0; i < 8; ++i) s += bf2f((u16)v[i]);
            }
            out[(size_t)(b0 + bb) * 400 + j] = s;
        }
    }

    for (int idx = tid; idx < 3328; idx += NTHR) {
        const int bb = idx / 1664, rr = idx - bb * 1664;
        const int fi = split * 52 + (rr >> 5), k = rr & 31;
        float qv = 0.f;
        if (fi < 200)
            qv = bf2f(resp[(size_t)(b0 + bb) * 6400 + fi * 32 + k]) * wq[fi * 32 + k];
        s_q[idx] = qv;
    }

    const int sbb = wid >> 2, sfil = wid & 3, sh = lane >> 5, sk = lane & 31;
    float xkr[20], xvr[20];
    #pragma unroll
    for (int i = 0; i < 20; ++i) {
        const int off = (sh * 20 + i) * 32 + sk;
        const float v = x0[(size_t)(b0 + sbb) * 1280 + off];
        xkr[i] = v * wk[off];
        xvr[i] = v * wv[off];
    }

    const int srow = sbb * 32 + sk;
    const int soff = sfil * 80 + sh * 40;
    const int sswz = (srow & 7) << 4;
    char* srb0 = (char*)s_XT[0] + srow * 384;
    char* srb1 = (char*)s_XT[1] + srow * 384;

    const int mg = wid & 1, ng = wid >> 1;
    const int nt0 = ng, nt1 = ng + 4;
    const int ntc = (ng < 3) ? 2 : 1;
    const int arow = mg * 32 + (lane & 31);
    const int aswz = (arow & 7) << 4;
    char* apb0 = (char*)s_XT[0] + arow * 384;
    char* apb1 = (char*)s_XT[1] + arow * 384;
    const int ah = (lane >> 5) * 16;

    f32x16 acc[2];
    #pragma unroll
    for (int t = 0; t < 2; ++t)
        #pragma unroll
        for (int r = 0; r < 16; ++r) acc[t][r] = 0.f;

    auto softmax_store = [&](char* rb, int ch) {
        const int fig = split * 52 + ch * 4 + sfil;
        if (fig < 200) {
            const float q = s_q[sbb * 1664 + (ch * 4 + sfil) * 32 + sk];
            float e[20], d = 0.f;
            #pragma unroll
            for (int i = 0; i < 20; ++i) { e[i] = __expf(xkr[i] * q); d += e[i]; }
            d += __shfl_xor(d, 32);
            const float rr = 1.0f / d;
            #pragma unroll
            for (int p = 0; p < 5; ++p) {
                u64 w = (u64)f2bf(e[4*p+0] * rr * xvr[4*p+0])
                      | ((u64)f2bf(e[4*p+1] * rr * xvr[4*p+1]) << 16)
                      | ((u64)f2bf(e[4*p+2] * rr * xvr[4*p+2]) << 32)
                      | ((u64)f2bf(e[4*p+3] * rr * xvr[4*p+3]) << 48);
                *reinterpret_cast<u64*>(rb + ((soff + p * 8) ^ sswz)) = w;
            }
        } else {
            #pragma unroll
            for (int p = 0; p < 5; ++p)
                *reinterpret_cast<u64*>(rb + ((soff + p * 8) ^ sswz)) = 0ull;
        }
    };

    __syncthreads();                           // s_q ready
    softmax_store(srb0, 0);
    __syncthreads();

    for (int ch = 0; ch < 13; ++ch) {
        if (ch + 1 < 13) softmax_store((ch & 1) ? srb0 : srb1, ch + 1);
        char* apb = (ch & 1) ? apb1 : apb0;
        #pragma unroll
        for (int ks = 0; ks < 10; ++ks) {
            bf16x8 a = *reinterpret_cast<const bf16x8*>(apb + ((ks * 32 + ah) ^ aswz));
            const int g = split * 130 + ch * 10 + ks;
            bf16x8 bf0 = *reinterpret_cast<const bf16x8*>(
                bp + ((size_t)(nt0 * 520 + g) * 64 + lane) * 8);
            acc[0] = __builtin_amdgcn_mfma_f32_32x32x16_bf16(a, bf0, acc[0], 0, 0, 0);
            if (ntc == 2) {
                bf16x8 bf1 = *reinterpret_cast<const bf16x8*>(
                    bp + ((size_t)(nt1 * 520 + g) * 64 + lane) * 8);
                acc[1] = __builtin_amdgcn_mfma_f32_32x32x16_bf16(a, bf1, acc[1], 0, 0, 0);
            }
        }
        __syncthreads();
    }

    #pragma unroll
    for (int t = 0; t < 2; ++t) {
        if (t < ntc) {
            float s = 0.f;
            #pragma unroll
            for (int r = 0; r < 16; ++r) s += acc[t][r];
            s += __shfl_xor(s, 32);
            const int nt = (t == 0) ? nt0 : nt1;
            const int j = nt * 32 + (lane & 31);
            if (lane < 32 && j < NJ)
                atomicAdd(&out[(size_t)(b0 + mg) * 400 + 200 + j], s);
        }
    }
}

extern "C" void kernel_launch(void* const* d_in, const int* in_sizes, int n_in,
                              void* d_out, int out_size, void* d_ws, size_t ws_size,
                              hipStream_t stream) {
    const float* x0  = (const float*)d_in[0];
    const float* wq0 = (const float*)d_in[1];
    const float* wk0 = (const float*)d_in[2];
    const float* wv0 = (const float*)d_in[3];
    const float* cw0 = (const float*)d_in[4];
    const float* wq1 = (const float*)d_in[5];
    const float* wk1 = (const float*)d_in[6];
    const float* wv1 = (const float*)d_in[7];
    const float* cw1 = (const float*)d_in[8];
    float* out = (float*)d_out;

    char* ws = (char*)d_ws;
    u16* resp = (u16*)ws;                          // 256*6400*2   = 3,276,800 B
    u16* bp0  = (u16*)(ws + 3276800);              // 7*100*512*2  =   716,800 B
    u16* bp1  = (u16*)(ws + 3276800 + 716800);     // 7*520*512*2  = 3,727,360 B

    hipMemsetAsync(d_out, 0, (size_t)out_size * 4, stream);

    pack_b<40> <<<dim3(10, 7), 256, 0, stream>>>(cw0, bp0, 100);
    pack_b<200><<<dim3(52, 7), 256, 0, stream>>>(cw1, bp1, 520);

    cin_layer0<<<256, NTHR, 0, stream>>>(x0, wq0, wk0, wv0, bp0, resp);
    cin_layer1<<<512, NTHR, 0, stream>>>(x0, resp, wq1, wk1, wv1, bp1, out);
}